// Round 6
// baseline (426.688 us; speedup 1.0000x reference)
//
#include <hip/hip_runtime.h>
#include <math.h>

namespace {
constexpr int kT = 16;
constexpr int kH = 56;
constexpr int kW = 56;
constexpr int kCAll = 256;
constexpr int kPlane = kH * kW;      // 3136
constexpr int kPlane4 = kPlane / 4;  // 784
}

// Gate layout (fp32, stored in out[frame 127]): plane index (n*2+g)*16 + t,
// each plane kPlane floats. Total = 256 planes = exactly one output frame.

// K0: zero the gate region (atomicAdd target).
__global__ __launch_bounds__(256)
void zero_gate_kernel(float4* __restrict__ g4) {
  const int i = blockIdx.x * 256 + threadIdx.x;
  if (i < 256 * kPlane4) g4[i] = make_float4(0.f, 0.f, 0.f, 0.f);
}

// K1: partial conv. Grid 2048 = (n:8, t:16, g:2, icq:8); each block reduces
// 4 ic x 3 kd = 12 stages over a full 56x56 plane. LDS: 58 rows x 16 slots
// of float4, XOR-swizzled (slot ^ (pr&15)) on BOTH write and read; logical
// slots 0/15 hold permanent zero halo. Each active thread computes 2x8 px
// (144 FMA per 16 ds_read_b128). Partials atomicAdd'ed into zeroed gate.
__global__ __launch_bounds__(256)
void gate_conv_kernel(const float* __restrict__ x,
                      const float* __restrict__ gamma,
                      const float* __restrict__ beta,
                      const float* __restrict__ mean,
                      const float* __restrict__ var,
                      const float* __restrict__ cw,
                      float* __restrict__ gate) {
  __shared__ float4 sm4[58 * 16];

  const int bid = blockIdx.x;          // 0..2047
  const int icq = bid & 7;
  const int g = (bid >> 3) & 1;
  const int t = (bid >> 4) & 15;
  const int n = bid >> 8;              // 0..7
  const int tid = threadIdx.x;

  // One-time zero init: halo (rows 0,57 and logical slots 0,15) stays zero.
  for (int i = tid; i < 58 * 16; i += 256)
    sm4[i] = make_float4(0.f, 0.f, 0.f, 0.f);

  const int cg = tid / 28;             // 0..6 valid when tid < 196
  const int r2 = tid % 28;             // output row pair 2*r2, 2*r2+1
  const bool active = (tid < 196);

  float acc0[8], acc1[8];
  #pragma unroll
  for (int p = 0; p < 8; ++p) { acc0[p] = 0.f; acc1[p] = 0.f; }

  // Stage s (0..11): icl = s/3, kd = s%3, ch = g*32 + icq*4 + icl, tt = t+kd-1.
  float4 pf0, pf1, pf2, pf3;

  auto prefetch = [&](int s) {
    const int icl = s / 3;
    const int kd = s - icl * 3;
    const int ch = g * 32 + icq * 4 + icl;
    const int tt = t + kd - 1;
    const bool valid = (tt >= 0 && tt < kT);
    if (valid) {
      const float4* src4 =
          (const float4*)(x + ((size_t)(n * kT + tt) * kCAll + ch) * kPlane);
      pf0 = src4[tid];
      pf1 = src4[tid + 256];
      pf2 = src4[tid + 512];
      pf3 = (tid < 784 - 768) ? src4[tid + 768] : make_float4(0.f, 0.f, 0.f, 0.f);
    } else {
      pf0 = pf1 = pf2 = pf3 = make_float4(0.f, 0.f, 0.f, 0.f);
    }
  };

  auto write_stage = [&](int s) {
    const int icl = s / 3;
    const int ch = g * 32 + icq * 4 + icl;
    const int kd = s - icl * 3;
    const int tt = t + kd - 1;
    const bool valid = (tt >= 0 && tt < kT);
    const float sc = gamma[ch] * rsqrtf(var[ch] + 1e-5f);
    const float sh = beta[ch] - mean[ch] * sc;
    float4 pf[4] = {pf0, pf1, pf2, pf3};
    #pragma unroll
    for (int j = 0; j < 4; ++j) {
      const int q = tid + j * 256;
      if (q < 784) {
        const int row = q / 14;          // hh 0..55
        const int sl = 1 + (q - row * 14);
        const int pr = row + 1;
        float4 w;
        if (valid) {
          w.x = fmaxf(0.f, fmaf(pf[j].x, sc, sh));
          w.y = fmaxf(0.f, fmaf(pf[j].y, sc, sh));
          w.z = fmaxf(0.f, fmaf(pf[j].z, sc, sh));
          w.w = fmaxf(0.f, fmaf(pf[j].w, sc, sh));
        } else {
          w = make_float4(0.f, 0.f, 0.f, 0.f);
        }
        sm4[pr * 16 + (sl ^ (pr & 15))] = w;
      }
    }
  };

  auto apply = [](float* a, const float* vc, const float* w3) {
    #pragma unroll
    for (int p = 0; p < 8; ++p)
      a[p] = fmaf(vc[p], w3[0], fmaf(vc[p + 1], w3[1], fmaf(vc[p + 2], w3[2], a[p])));
  };

  prefetch(0);  // fill the pipeline (round-5 bug: this call was missing)

  for (int s = 0; s < 12; ++s) {
    __syncthreads();                 // init / prior compute done reading LDS
    write_stage(s);
    __syncthreads();
    if (s < 11) prefetch(s + 1);     // overlaps with compute below
    if (active) {
      const int icl = s / 3;
      const int kd = s - icl * 3;
      const int tt = t + kd - 1;
      if (tt >= 0 && tt < kT) {
        const int ch = g * 32 + icq * 4 + icl;
        const float* wb = cw + ch * 27 + kd * 9;
        float wk[9];
        #pragma unroll
        for (int j = 0; j < 9; ++j) wk[j] = wb[j];
        #pragma unroll
        for (int ir = 0; ir < 4; ++ir) {
          const int pr = 2 * r2 + ir;      // input padded row, 0..57
          const int base = pr * 16;
          const int swz = pr & 15;
          const float4 L0 = sm4[base + ((2 * cg + 0) ^ swz)];
          const float4 L1 = sm4[base + ((2 * cg + 1) ^ swz)];
          const float4 L2 = sm4[base + ((2 * cg + 2) ^ swz)];
          const float4 L3 = sm4[base + ((2 * cg + 3) ^ swz)];
          const float vc[10] = {L0.w, L1.x, L1.y, L1.z, L1.w,
                                L2.x, L2.y, L2.z, L2.w, L3.x};
          if (ir == 0) {
            apply(acc0, vc, wk + 0);
          } else if (ir == 1) {
            apply(acc0, vc, wk + 3); apply(acc1, vc, wk + 0);
          } else if (ir == 2) {
            apply(acc0, vc, wk + 6); apply(acc1, vc, wk + 3);
          } else {
            apply(acc1, vc, wk + 6);
          }
        }
      }
    }
  }

  if (active) {
    float* gp = gate + ((size_t)(n * 2 + g) * kT + t) * kPlane
                     + (2 * r2) * kW + cg * 8;
    #pragma unroll
    for (int p = 0; p < 8; ++p) atomicAdd(gp + p, acc0[p]);
    #pragma unroll
    for (int p = 0; p < 8; ++p) atomicAdd(gp + kW + p, acc1[p]);
  }
}

// K1b: gate = tanh(gate + bias[g])
__global__ __launch_bounds__(256)
void gate_finish_kernel(float* __restrict__ gate, const float* __restrict__ cb) {
  const int idx = blockIdx.x * 256 + threadIdx.x;
  if (idx >= 256 * kPlane) return;
  const int plane = idx / kPlane;      // (n*2+g)*16 + t
  const int g = (plane >> 4) & 1;
  gate[idx] = tanhf(gate[idx] + cb[g]);
}

// K1.5: copy the 3 gate planes frame-127 outputs need (g0[n7,t15]=239,
// g1[n7,t14]=254, g1[n7,t15]=255) into hole H = frame 126, channels 64..66.
__global__ __launch_bounds__(256)
void copy_gate_slice_kernel(float4* __restrict__ o4) {
  const int j = blockIdx.x * 256 + threadIdx.x;
  if (j >= 3 * kPlane4) return;
  const int q = j / kPlane4;
  const int rr = j - q * kPlane4;
  const int pidx = (q == 0) ? 239 : (q == 1 ? 254 : 255);
  const size_t G1 = (size_t)127 * kCAll * kPlane4;
  const size_t H = ((size_t)126 * kCAll + 64) * kPlane4;
  o4[H + j] = o4[G1 + (size_t)pidx * kPlane4 + rr];
}

// K2: frames 0..126. c>=64 passthrough (skip hole H); c<64 gated shift.
//   half0 (left):  out[t] = g0[t+1]*x[t+1] + x[t] - g0[t]*x[t]
//   half1 (right): out[t] = g1[t-1]*x[t-1] + x[t] - g1[t]*x[t]
//   channel regroup inverse: out k -> pre channel (k&1)*16 + (k>>1)
__global__ __launch_bounds__(256)
void shift_main_kernel(const float4* __restrict__ x4,
                       const float4* __restrict__ g4,
                       float4* __restrict__ o4) {
  const size_t total = (size_t)127 * kCAll * kPlane4;
  const size_t idx = (size_t)blockIdx.x * 256 + threadIdx.x;
  if (idx >= total) return;

  const int p = (int)(idx % kPlane4);
  const size_t rest = idx / kPlane4;
  const int c = (int)(rest % kCAll);
  const int f = (int)(rest / kCAll);

  if (c >= 64) {
    if (f == 126 && c <= 66) return;  // hole H holds gate slice until K3
    o4[idx] = x4[idx];
    return;
  }

  const int n = f >> 4;
  const int t = f & 15;
  const int half = c >> 5;
  const int k = c & 31;
  const int m = ((k & 1) << 4) + (k >> 1);
  const int src_ch = half * 32 + m;

  const size_t xcur = ((size_t)f * kCAll + src_ch) * kPlane4 + p;
  const size_t gbase = (size_t)(n * 2 + half) * kT * kPlane4 + p;

  const float4 xc = x4[xcur];
  const float4 gc = g4[gbase + (size_t)t * kPlane4];
  float4 y = make_float4(0.f, 0.f, 0.f, 0.f);
  if (half == 0) {
    if (t < kT - 1) {
      const float4 xn = x4[xcur + (size_t)kCAll * kPlane4];
      const float4 gn = g4[gbase + (size_t)(t + 1) * kPlane4];
      y.x = gn.x * xn.x; y.y = gn.y * xn.y; y.z = gn.z * xn.z; y.w = gn.w * xn.w;
    }
  } else {
    if (t > 0) {
      const float4 xp = x4[xcur - (size_t)kCAll * kPlane4];
      const float4 gp = g4[gbase + (size_t)(t - 1) * kPlane4];
      y.x = gp.x * xp.x; y.y = gp.y * xp.y; y.z = gp.z * xp.z; y.w = gp.w * xp.w;
    }
  }
  float4 res;
  res.x = y.x + (xc.x - gc.x * xc.x);
  res.y = y.y + (xc.y - gc.y * xc.y);
  res.z = y.z + (xc.z - gc.z * xc.z);
  res.w = y.w + (xc.w - gc.w * xc.w);
  o4[idx] = res;
}

// K3: frame 127 (n=7, t=15). Reads gate slices from hole H; overwrites the
// old gate region (frame 127) with final outputs.
__global__ __launch_bounds__(256)
void last_frame_kernel(const float4* __restrict__ x4,
                       float4* o4) {
  const int idx = blockIdx.x * 256 + threadIdx.x;
  if (idx >= kCAll * kPlane4) return;
  const size_t F127 = (size_t)127 * kCAll * kPlane4;
  const int p = idx % kPlane4;
  const int c = idx / kPlane4;
  if (c >= 64) { o4[F127 + idx] = x4[F127 + idx]; return; }

  const size_t H = ((size_t)126 * kCAll + 64) * kPlane4;
  const int half = c >> 5;
  const int k = c & 31;
  const int m = ((k & 1) << 4) + (k >> 1);
  const int src_ch = half * 32 + m;

  const float4 xc = x4[F127 + (size_t)src_ch * kPlane4 + p];
  float4 gc;
  float4 y = make_float4(0.f, 0.f, 0.f, 0.f);
  if (half == 0) {
    gc = o4[H + 0 * kPlane4 + p];                 // g0[t=15]; t+1 padded -> y=0
  } else {
    gc = o4[H + 2 * kPlane4 + p];                 // g1[t=15]
    const float4 gp = o4[H + 1 * kPlane4 + p];    // g1[t=14]
    const float4 xp = x4[((size_t)126 * kCAll + src_ch) * kPlane4 + p];
    y.x = gp.x * xp.x; y.y = gp.y * xp.y; y.z = gp.z * xp.z; y.w = gp.w * xp.w;
  }
  float4 res;
  res.x = y.x + (xc.x - gc.x * xc.x);
  res.y = y.y + (xc.y - gc.y * xc.y);
  res.z = y.z + (xc.z - gc.z * xc.z);
  res.w = y.w + (xc.w - gc.w * xc.w);
  o4[F127 + idx] = res;
}

// K4: hole H gets its real passthrough values.
__global__ __launch_bounds__(256)
void fix_hole_kernel(const float4* __restrict__ x4, float4* __restrict__ o4) {
  const int j = blockIdx.x * 256 + threadIdx.x;
  if (j >= 3 * kPlane4) return;
  const size_t H = ((size_t)126 * kCAll + 64) * kPlane4;
  o4[H + j] = x4[H + j];
}

extern "C" void kernel_launch(void* const* d_in, const int* in_sizes, int n_in,
                              void* d_out, int out_size, void* d_ws, size_t ws_size,
                              hipStream_t stream) {
  const float* x     = (const float*)d_in[0];
  const float* gamma = (const float*)d_in[1];
  const float* beta  = (const float*)d_in[2];
  const float* mean  = (const float*)d_in[3];
  const float* var   = (const float*)d_in[4];
  const float* cw    = (const float*)d_in[5];
  const float* cb    = (const float*)d_in[6];
  float* out = (float*)d_out;

  // Gate tensor lives in the frame-127 region of the output (exactly 1 frame).
  float* gate = out + (size_t)127 * kCAll * kPlane;

  zero_gate_kernel<<<(256 * kPlane4 + 255) / 256, 256, 0, stream>>>((float4*)gate);

  // 8 n * 16 t * 2 g * 8 icq = 2048 blocks
  gate_conv_kernel<<<2048, 256, 0, stream>>>(x, gamma, beta, mean, var, cw, gate);
  gate_finish_kernel<<<(256 * kPlane + 255) / 256, 256, 0, stream>>>(gate, cb);
  copy_gate_slice_kernel<<<10, 256, 0, stream>>>((float4*)out);

  const size_t total4 = (size_t)127 * kCAll * kPlane4;  // 25,489,408
  shift_main_kernel<<<(unsigned)((total4 + 255) / 256), 256, 0, stream>>>(
      (const float4*)x, (const float4*)gate, (float4*)out);

  last_frame_kernel<<<(kCAll * kPlane4 + 255) / 256, 256, 0, stream>>>(
      (const float4*)x, (float4*)out);
  fix_hole_kernel<<<10, 256, 0, stream>>>((const float4*)x, (float4*)out);
}

// Round 7
// 268.685 us; speedup vs baseline: 1.5881x; 1.5881x over previous
//
#include <hip/hip_runtime.h>
#include <math.h>

namespace {
constexpr int kT = 16;
constexpr int kH = 56;
constexpr int kW = 56;
constexpr int kCAll = 256;
constexpr int kPlane = kH * kW;      // 3136
constexpr int kPlane4 = kPlane / 4;  // 784
}

// Gate layout (fp32, stored in out[frame 127]): plane index (n*2+g)*16 + t,
// each plane kPlane floats. Total = 256 planes = exactly one output frame.

// K1: gate = tanh(conv3d(relu(bn(x[:, :64])), groups=2) + b)
// Grid 512 = (n:8, t:16, g:2, stripe:2); block = 512 threads = 8 waves.
// Wave w owns ic = w*4..w*4+3 (x kd=3 -> 12 slices), staged into a
// WAVE-PRIVATE LDS buffer: 30 rows x 16 float4-blocks, block index XOR'd
// with (row&15); blocks 0/15 (and stripe-invalid rows) stay zero = halo.
// Lane (r=lane>>1, h=lane&1) computes 28 px of output row h0+r, cols
// h*28..h*28+27, accumulating in registers. Final: 8 wave-partials reduced
// through LDS (buffer reused), tanh+bias fused into the store. No atomics.
__global__ __launch_bounds__(512, 4)
void gate_conv_kernel(const float* __restrict__ x,
                      const float* __restrict__ gamma,
                      const float* __restrict__ beta,
                      const float* __restrict__ mean,
                      const float* __restrict__ var,
                      const float* __restrict__ cw,
                      const float* __restrict__ cb,
                      float* __restrict__ gate) {
  __shared__ float4 sm4[8 * 480];      // 8 waves x (30 rows x 16 blocks)

  const int bid = blockIdx.x;          // (((n*16+t)*2+g)*2+stripe)
  const int stripe = bid & 1;
  const int g = (bid >> 1) & 1;
  const int t = (bid >> 2) & 15;
  const int n = bid >> 6;              // 0..7
  const int h0 = stripe * 28;
  const int tid = threadIdx.x;
  const int wid = tid >> 6;            // wave 0..7
  const int lane = tid & 63;
  const int r = lane >> 1;             // 0..31 (active < 28)
  const int h = lane & 1;              // column half
  const int wb = wid * 480;            // wave LDS base (float4 units)

  for (int i = tid; i < 8 * 480; i += 512)
    sm4[i] = make_float4(0.f, 0.f, 0.f, 0.f);
  // first in-loop barrier orders this init before any staging read

  float acc[28];
  #pragma unroll
  for (int p = 0; p < 28; ++p) acc[p] = 0.f;

  for (int il = 0; il < 4; ++il) {
    const int ch = g * 32 + wid * 4 + il;
    const float sc = gamma[ch] * rsqrtf(var[ch] + 1e-5f);
    const float sh = beta[ch] - mean[ch] * sc;
    for (int kd = 0; kd < 3; ++kd) {
      const int tt = t + kd - 1;
      if (tt < 0 || tt >= kT) continue;          // block-uniform skip
      __syncthreads();                           // prior compute done reading
      const float4* src4 =
          (const float4*)x + ((size_t)(n * kT + tt) * kCAll + ch) * kPlane4;
      for (int j = lane; j < 420; j += 64) {     // 30 rows x 14 data blocks
        const int rr = j / 14;
        const int fb = j - rr * 14;
        const int gr = h0 + rr - 1;
        if ((unsigned)gr < (unsigned)kH) {
          float4 a = src4[gr * 14 + fb];
          a.x = fmaxf(0.f, fmaf(a.x, sc, sh));
          a.y = fmaxf(0.f, fmaf(a.y, sc, sh));
          a.z = fmaxf(0.f, fmaf(a.z, sc, sh));
          a.w = fmaxf(0.f, fmaf(a.w, sc, sh));
          sm4[wb + rr * 16 + ((fb + 1) ^ (rr & 15))] = a;
        }
      }
      __syncthreads();                           // staging visible to own wave
      if (r < 28) {
        const float* wbp = cw + ch * 27 + kd * 9;
        float wk[9];
        #pragma unroll
        for (int j = 0; j < 9; ++j) wk[j] = wbp[j];
        #pragma unroll
        for (int kh = 0; kh < 3; ++kh) {
          const int prow = r + kh;               // padded row 0..29
          const int swz = prow & 15;
          const int base = wb + prow * 16;
          float f[36];                           // px (28h-4) .. (28h+31)
          #pragma unroll
          for (int jj = 0; jj < 9; ++jj) {
            const float4 B = sm4[base + ((7 * h + jj) ^ swz)];
            f[4 * jj + 0] = B.x; f[4 * jj + 1] = B.y;
            f[4 * jj + 2] = B.z; f[4 * jj + 3] = B.w;
          }
          const float w0 = wk[kh * 3 + 0];
          const float w1 = wk[kh * 3 + 1];
          const float w2 = wk[kh * 3 + 2];
          #pragma unroll
          for (int p = 0; p < 28; ++p)
            acc[p] = fmaf(f[p + 3], w0,
                     fmaf(f[p + 4], w1, fmaf(f[p + 5], w2, acc[p])));
        }
      }
    }
  }

  // Cross-wave reduction: reuse sm4 as a float region [8][1568].
  __syncthreads();                               // all compute done
  float* smf = (float*)sm4;
  if (r < 28) {
    const int q0 = r * 56 + h * 28;
    #pragma unroll
    for (int p = 0; p < 28; ++p) smf[wid * 1568 + q0 + p] = acc[p];
  }
  __syncthreads();
  const float bias = cb[g];
  float* gp = gate + ((size_t)(n * 2 + g) * kT + t) * kPlane + h0 * kW;
  for (int q = tid; q < 1568; q += 512) {
    float s = 0.f;
    #pragma unroll
    for (int w = 0; w < 8; ++w) s += smf[w * 1568 + q];
    gp[q] = tanhf(s + bias);
  }
}

// K1.5: copy the 3 gate planes frame-127 outputs need (g0[n7,t15]=239,
// g1[n7,t14]=254, g1[n7,t15]=255) into hole H = frame 126, channels 64..66.
__global__ __launch_bounds__(256)
void copy_gate_slice_kernel(float4* __restrict__ o4) {
  const int j = blockIdx.x * 256 + threadIdx.x;
  if (j >= 3 * kPlane4) return;
  const int q = j / kPlane4;
  const int rr = j - q * kPlane4;
  const int pidx = (q == 0) ? 239 : (q == 1 ? 254 : 255);
  const size_t G1 = (size_t)127 * kCAll * kPlane4;
  const size_t H = ((size_t)126 * kCAll + 64) * kPlane4;
  o4[H + j] = o4[G1 + (size_t)pidx * kPlane4 + rr];
}

// K2: frames 0..126. c>=64 passthrough (skip hole H); c<64 gated shift.
//   half0 (left):  out[t] = g0[t+1]*x[t+1] + x[t] - g0[t]*x[t]
//   half1 (right): out[t] = g1[t-1]*x[t-1] + x[t] - g1[t]*x[t]
//   channel regroup inverse: out k -> pre channel (k&1)*16 + (k>>1)
__global__ __launch_bounds__(256)
void shift_main_kernel(const float4* __restrict__ x4,
                       const float4* __restrict__ g4,
                       float4* __restrict__ o4) {
  const size_t total = (size_t)127 * kCAll * kPlane4;
  const size_t idx = (size_t)blockIdx.x * 256 + threadIdx.x;
  if (idx >= total) return;

  const int p = (int)(idx % kPlane4);
  const size_t rest = idx / kPlane4;
  const int c = (int)(rest % kCAll);
  const int f = (int)(rest / kCAll);

  if (c >= 64) {
    if (f == 126 && c <= 66) return;  // hole H holds gate slice until K3
    o4[idx] = x4[idx];
    return;
  }

  const int n = f >> 4;
  const int t = f & 15;
  const int half = c >> 5;
  const int k = c & 31;
  const int m = ((k & 1) << 4) + (k >> 1);
  const int src_ch = half * 32 + m;

  const size_t xcur = ((size_t)f * kCAll + src_ch) * kPlane4 + p;
  const size_t gbase = (size_t)(n * 2 + half) * kT * kPlane4 + p;

  const float4 xc = x4[xcur];
  const float4 gc = g4[gbase + (size_t)t * kPlane4];
  float4 y = make_float4(0.f, 0.f, 0.f, 0.f);
  if (half == 0) {
    if (t < kT - 1) {
      const float4 xn = x4[xcur + (size_t)kCAll * kPlane4];
      const float4 gn = g4[gbase + (size_t)(t + 1) * kPlane4];
      y.x = gn.x * xn.x; y.y = gn.y * xn.y; y.z = gn.z * xn.z; y.w = gn.w * xn.w;
    }
  } else {
    if (t > 0) {
      const float4 xp = x4[xcur - (size_t)kCAll * kPlane4];
      const float4 gp = g4[gbase + (size_t)(t - 1) * kPlane4];
      y.x = gp.x * xp.x; y.y = gp.y * xp.y; y.z = gp.z * xp.z; y.w = gp.w * xp.w;
    }
  }
  float4 res;
  res.x = y.x + (xc.x - gc.x * xc.x);
  res.y = y.y + (xc.y - gc.y * xc.y);
  res.z = y.z + (xc.z - gc.z * xc.z);
  res.w = y.w + (xc.w - gc.w * xc.w);
  o4[idx] = res;
}

// K3: frame 127 (n=7, t=15). Reads gate slices from hole H; overwrites the
// old gate region (frame 127) with final outputs.
__global__ __launch_bounds__(256)
void last_frame_kernel(const float4* __restrict__ x4,
                       float4* o4) {
  const int idx = blockIdx.x * 256 + threadIdx.x;
  if (idx >= kCAll * kPlane4) return;
  const size_t F127 = (size_t)127 * kCAll * kPlane4;
  const int p = idx % kPlane4;
  const int c = idx / kPlane4;
  if (c >= 64) { o4[F127 + idx] = x4[F127 + idx]; return; }

  const size_t H = ((size_t)126 * kCAll + 64) * kPlane4;
  const int half = c >> 5;
  const int k = c & 31;
  const int m = ((k & 1) << 4) + (k >> 1);
  const int src_ch = half * 32 + m;

  const float4 xc = x4[F127 + (size_t)src_ch * kPlane4 + p];
  float4 gc;
  float4 y = make_float4(0.f, 0.f, 0.f, 0.f);
  if (half == 0) {
    gc = o4[H + 0 * kPlane4 + p];                 // g0[t=15]; t+1 padded -> y=0
  } else {
    gc = o4[H + 2 * kPlane4 + p];                 // g1[t=15]
    const float4 gp = o4[H + 1 * kPlane4 + p];    // g1[t=14]
    const float4 xp = x4[((size_t)126 * kCAll + src_ch) * kPlane4 + p];
    y.x = gp.x * xp.x; y.y = gp.y * xp.y; y.z = gp.z * xp.z; y.w = gp.w * xp.w;
  }
  float4 res;
  res.x = y.x + (xc.x - gc.x * xc.x);
  res.y = y.y + (xc.y - gc.y * xc.y);
  res.z = y.z + (xc.z - gc.z * xc.z);
  res.w = y.w + (xc.w - gc.w * xc.w);
  o4[F127 + idx] = res;
}

// K4: hole H gets its real passthrough values.
__global__ __launch_bounds__(256)
void fix_hole_kernel(const float4* __restrict__ x4, float4* __restrict__ o4) {
  const int j = blockIdx.x * 256 + threadIdx.x;
  if (j >= 3 * kPlane4) return;
  const size_t H = ((size_t)126 * kCAll + 64) * kPlane4;
  o4[H + j] = x4[H + j];
}

extern "C" void kernel_launch(void* const* d_in, const int* in_sizes, int n_in,
                              void* d_out, int out_size, void* d_ws, size_t ws_size,
                              hipStream_t stream) {
  const float* x     = (const float*)d_in[0];
  const float* gamma = (const float*)d_in[1];
  const float* beta  = (const float*)d_in[2];
  const float* mean  = (const float*)d_in[3];
  const float* var   = (const float*)d_in[4];
  const float* cw    = (const float*)d_in[5];
  const float* cb    = (const float*)d_in[6];
  float* out = (float*)d_out;

  // Gate tensor lives in the frame-127 region of the output (exactly 1 frame).
  float* gate = out + (size_t)127 * kCAll * kPlane;

  // 8 n * 16 t * 2 g * 2 stripes = 512 blocks, 512 threads (8 waves)
  gate_conv_kernel<<<512, 512, 0, stream>>>(x, gamma, beta, mean, var, cw, cb, gate);
  copy_gate_slice_kernel<<<10, 256, 0, stream>>>((float4*)out);

  const size_t total4 = (size_t)127 * kCAll * kPlane4;  // 25,489,408
  shift_main_kernel<<<(unsigned)((total4 + 255) / 256), 256, 0, stream>>>(
      (const float4*)x, (const float4*)gate, (float4*)out);

  last_frame_kernel<<<(kCAll * kPlane4 + 255) / 256, 256, 0, stream>>>(
      (const float4*)x, (float4*)out);
  fix_hole_kernel<<<10, 256, 0, stream>>>((const float4*)x, (float4*)out);
}

// Round 8
// 244.798 us; speedup vs baseline: 1.7430x; 1.0976x over previous
//
#include <hip/hip_runtime.h>
#include <math.h>

namespace {
constexpr int kT = 16;
constexpr int kH = 56;
constexpr int kW = 56;
constexpr int kCAll = 256;
constexpr int kPlane = kH * kW;      // 3136
constexpr int kPlane4 = kPlane / 4;  // 784
}

// Gate layout (fp32, stored in out[frame 127]): plane index (n*2+g)*16 + t,
// each plane kPlane floats. Total = 256 planes = exactly one output frame.

// K1: gate = tanh(conv3d(relu(bn(x[:, :64])), groups=2) + b)
// Grid 512 = (n:8, t:16, g:2, stripe:2); block = 512 threads = 8 waves.
// Wave w owns ic = w*4..w*4+3 (x kd=3 -> 12 slices), staged into a
// WAVE-PRIVATE LDS buffer (30 rows x 16 float4-blocks, idx XOR (row&15)).
// SELF-TIMED: no __syncthreads in the slice loop — wave-internal ordering
// via s_waitcnt lgkmcnt(0) + sched_barrier (buffers are wave-private).
// Final cross-wave reduction uses the only 2 barriers, tanh+bias fused.
__global__ __launch_bounds__(512, 4)
void gate_conv_kernel(const float* __restrict__ x,
                      const float* __restrict__ gamma,
                      const float* __restrict__ beta,
                      const float* __restrict__ mean,
                      const float* __restrict__ var,
                      const float* __restrict__ cw,
                      const float* __restrict__ cb,
                      float* __restrict__ gate) {
  __shared__ float4 sm4[8 * 480];      // 8 waves x (30 rows x 16 blocks)

  const int bid = blockIdx.x;          // (((n*16+t)*2+g)*2+stripe)
  const int stripe = bid & 1;
  const int g = (bid >> 1) & 1;
  const int t = (bid >> 2) & 15;
  const int n = bid >> 6;              // 0..7
  const int h0 = stripe * 28;
  const int tid = threadIdx.x;
  const int wid = tid >> 6;            // wave 0..7
  const int lane = tid & 63;
  const int r = lane >> 1;             // 0..31 (active < 28)
  const int h = lane & 1;              // column half
  const int wb = wid * 480;            // wave LDS base (float4 units)

  // WAVE-PRIVATE zero init (halo rows/slots stay zero forever).
  for (int i = lane; i < 480; i += 64)
    sm4[wb + i] = make_float4(0.f, 0.f, 0.f, 0.f);

  // Precomputed staging map: up to 7 strided (row, block) slots per lane.
  int rr_u[7], fb_u[7], go_u[7];       // LDS row, LDS block, global offset
  bool val_u[7];
  #pragma unroll
  for (int u = 0; u < 7; ++u) {
    const int j = lane + u * 64;
    bool v = (j < 420);
    int rr = 0, fb = 0, go = 0;
    if (v) {
      rr = j / 14;
      fb = j - rr * 14;
      const int gr = h0 + rr - 1;
      v = ((unsigned)gr < (unsigned)kH);
      if (v) go = gr * 14 + fb;
    }
    rr_u[u] = rr; fb_u[u] = fb; go_u[u] = go; val_u[u] = v;
  }

  float acc[28];
  #pragma unroll
  for (int p = 0; p < 28; ++p) acc[p] = 0.f;

  // order init-writes before first slice's reads (same wave)
  asm volatile("s_waitcnt lgkmcnt(0)" ::: "memory");
  __builtin_amdgcn_sched_barrier(0);

  for (int il = 0; il < 4; ++il) {
    const int ch = g * 32 + wid * 4 + il;
    const float sc = gamma[ch] * rsqrtf(var[ch] + 1e-5f);
    const float sh = beta[ch] - mean[ch] * sc;
    for (int kd = 0; kd < 3; ++kd) {
      const int tt = t + kd - 1;
      if (tt < 0 || tt >= kT) continue;          // block-uniform skip
      const float4* src4 =
          (const float4*)x + ((size_t)(n * kT + tt) * kCAll + ch) * kPlane4;
      // stage: global -> reg -> BN/ReLU -> wave-private LDS (swizzled)
      float4 stg[7];
      #pragma unroll
      for (int u = 0; u < 7; ++u)
        stg[u] = val_u[u] ? src4[go_u[u]] : make_float4(0.f, 0.f, 0.f, 0.f);
      #pragma unroll
      for (int u = 0; u < 7; ++u) {
        if (val_u[u]) {
          float4 a = stg[u];
          a.x = fmaxf(0.f, fmaf(a.x, sc, sh));
          a.y = fmaxf(0.f, fmaf(a.y, sc, sh));
          a.z = fmaxf(0.f, fmaf(a.z, sc, sh));
          a.w = fmaxf(0.f, fmaf(a.w, sc, sh));
          sm4[wb + rr_u[u] * 16 + ((fb_u[u] + 1) ^ (rr_u[u] & 15))] = a;
        }
      }
      // wave-internal fence: ds_writes complete before ds_reads below
      asm volatile("s_waitcnt lgkmcnt(0)" ::: "memory");
      __builtin_amdgcn_sched_barrier(0);
      if (r < 28) {
        const float* wbp = cw + ch * 27 + kd * 9;
        float wk[9];
        #pragma unroll
        for (int j = 0; j < 9; ++j) wk[j] = wbp[j];
        #pragma unroll
        for (int kh = 0; kh < 3; ++kh) {
          const int prow = r + kh;               // padded row 0..29
          const int swz = prow & 15;
          const int base = wb + prow * 16;
          float f[36];                           // px (28h-4) .. (28h+31)
          #pragma unroll
          for (int jj = 0; jj < 9; ++jj) {
            const float4 B = sm4[base + ((7 * h + jj) ^ swz)];
            f[4 * jj + 0] = B.x; f[4 * jj + 1] = B.y;
            f[4 * jj + 2] = B.z; f[4 * jj + 3] = B.w;
          }
          const float w0 = wk[kh * 3 + 0];
          const float w1 = wk[kh * 3 + 1];
          const float w2 = wk[kh * 3 + 2];
          #pragma unroll
          for (int p = 0; p < 28; ++p)
            acc[p] = fmaf(f[p + 3], w0,
                     fmaf(f[p + 4], w1, fmaf(f[p + 5], w2, acc[p])));
        }
      }
      // WAR fence: reads done before next slice's ds_writes overwrite
      asm volatile("s_waitcnt lgkmcnt(0)" ::: "memory");
      __builtin_amdgcn_sched_barrier(0);
    }
  }

  // Cross-wave reduction: reuse sm4 as a float region [8][1568].
  __syncthreads();                               // all waves' compute done
  float* smf = (float*)sm4;
  if (r < 28) {
    const int q0 = r * 56 + h * 28;
    #pragma unroll
    for (int p = 0; p < 28; ++p) smf[wid * 1568 + q0 + p] = acc[p];
  }
  __syncthreads();
  const float bias = cb[g];
  float* gp = gate + ((size_t)(n * 2 + g) * kT + t) * kPlane + h0 * kW;
  for (int q = tid; q < 1568; q += 512) {
    float s = 0.f;
    #pragma unroll
    for (int w = 0; w < 8; ++w) s += smf[w * 1568 + q];
    gp[q] = tanhf(s + bias);
  }
}

// K1.5: copy the 3 gate planes frame-127 outputs need (g0[n7,t15]=239,
// g1[n7,t14]=254, g1[n7,t15]=255) into hole H = frame 126, channels 64..66.
__global__ __launch_bounds__(256)
void copy_gate_slice_kernel(float4* __restrict__ o4) {
  const int j = blockIdx.x * 256 + threadIdx.x;
  if (j >= 3 * kPlane4) return;
  const int q = j / kPlane4;
  const int rr = j - q * kPlane4;
  const int pidx = (q == 0) ? 239 : (q == 1 ? 254 : 255);
  const size_t G1 = (size_t)127 * kCAll * kPlane4;
  const size_t H = ((size_t)126 * kCAll + 64) * kPlane4;
  o4[H + j] = o4[G1 + (size_t)pidx * kPlane4 + rr];
}

// K2: frames 0..126. c>=64 passthrough (skip hole H); c<64 gated shift.
//   half0 (left):  out[t] = g0[t+1]*x[t+1] + x[t] - g0[t]*x[t]
//   half1 (right): out[t] = g1[t-1]*x[t-1] + x[t] - g1[t]*x[t]
//   channel regroup inverse: out k -> pre channel (k&1)*16 + (k>>1)
__global__ __launch_bounds__(256)
void shift_main_kernel(const float4* __restrict__ x4,
                       const float4* __restrict__ g4,
                       float4* __restrict__ o4) {
  const size_t total = (size_t)127 * kCAll * kPlane4;
  const size_t idx = (size_t)blockIdx.x * 256 + threadIdx.x;
  if (idx >= total) return;

  const int p = (int)(idx % kPlane4);
  const size_t rest = idx / kPlane4;
  const int c = (int)(rest % kCAll);
  const int f = (int)(rest / kCAll);

  if (c >= 64) {
    if (f == 126 && c <= 66) return;  // hole H holds gate slice until K3
    o4[idx] = x4[idx];
    return;
  }

  const int n = f >> 4;
  const int t = f & 15;
  const int half = c >> 5;
  const int k = c & 31;
  const int m = ((k & 1) << 4) + (k >> 1);
  const int src_ch = half * 32 + m;

  const size_t xcur = ((size_t)f * kCAll + src_ch) * kPlane4 + p;
  const size_t gbase = (size_t)(n * 2 + half) * kT * kPlane4 + p;

  const float4 xc = x4[xcur];
  const float4 gc = g4[gbase + (size_t)t * kPlane4];
  float4 y = make_float4(0.f, 0.f, 0.f, 0.f);
  if (half == 0) {
    if (t < kT - 1) {
      const float4 xn = x4[xcur + (size_t)kCAll * kPlane4];
      const float4 gn = g4[gbase + (size_t)(t + 1) * kPlane4];
      y.x = gn.x * xn.x; y.y = gn.y * xn.y; y.z = gn.z * xn.z; y.w = gn.w * xn.w;
    }
  } else {
    if (t > 0) {
      const float4 xp = x4[xcur - (size_t)kCAll * kPlane4];
      const float4 gp = g4[gbase + (size_t)(t - 1) * kPlane4];
      y.x = gp.x * xp.x; y.y = gp.y * xp.y; y.z = gp.z * xp.z; y.w = gp.w * xp.w;
    }
  }
  float4 res;
  res.x = y.x + (xc.x - gc.x * xc.x);
  res.y = y.y + (xc.y - gc.y * xc.y);
  res.z = y.z + (xc.z - gc.z * xc.z);
  res.w = y.w + (xc.w - gc.w * xc.w);
  o4[idx] = res;
}

// K3: frame 127 (n=7, t=15). Reads gate slices from hole H; overwrites the
// old gate region (frame 127) with final outputs.
__global__ __launch_bounds__(256)
void last_frame_kernel(const float4* __restrict__ x4,
                       float4* o4) {
  const int idx = blockIdx.x * 256 + threadIdx.x;
  if (idx >= kCAll * kPlane4) return;
  const size_t F127 = (size_t)127 * kCAll * kPlane4;
  const int p = idx % kPlane4;
  const int c = idx / kPlane4;
  if (c >= 64) { o4[F127 + idx] = x4[F127 + idx]; return; }

  const size_t H = ((size_t)126 * kCAll + 64) * kPlane4;
  const int half = c >> 5;
  const int k = c & 31;
  const int m = ((k & 1) << 4) + (k >> 1);
  const int src_ch = half * 32 + m;

  const float4 xc = x4[F127 + (size_t)src_ch * kPlane4 + p];
  float4 gc;
  float4 y = make_float4(0.f, 0.f, 0.f, 0.f);
  if (half == 0) {
    gc = o4[H + 0 * kPlane4 + p];                 // g0[t=15]; t+1 padded -> y=0
  } else {
    gc = o4[H + 2 * kPlane4 + p];                 // g1[t=15]
    const float4 gp = o4[H + 1 * kPlane4 + p];    // g1[t=14]
    const float4 xp = x4[((size_t)126 * kCAll + src_ch) * kPlane4 + p];
    y.x = gp.x * xp.x; y.y = gp.y * xp.y; y.z = gp.z * xp.z; y.w = gp.w * xp.w;
  }
  float4 res;
  res.x = y.x + (xc.x - gc.x * xc.x);
  res.y = y.y + (xc.y - gc.y * xc.y);
  res.z = y.z + (xc.z - gc.z * xc.z);
  res.w = y.w + (xc.w - gc.w * xc.w);
  o4[F127 + idx] = res;
}

// K4: hole H gets its real passthrough values.
__global__ __launch_bounds__(256)
void fix_hole_kernel(const float4* __restrict__ x4, float4* __restrict__ o4) {
  const int j = blockIdx.x * 256 + threadIdx.x;
  if (j >= 3 * kPlane4) return;
  const size_t H = ((size_t)126 * kCAll + 64) * kPlane4;
  o4[H + j] = x4[H + j];
}

extern "C" void kernel_launch(void* const* d_in, const int* in_sizes, int n_in,
                              void* d_out, int out_size, void* d_ws, size_t ws_size,
                              hipStream_t stream) {
  const float* x     = (const float*)d_in[0];
  const float* gamma = (const float*)d_in[1];
  const float* beta  = (const float*)d_in[2];
  const float* mean  = (const float*)d_in[3];
  const float* var   = (const float*)d_in[4];
  const float* cw    = (const float*)d_in[5];
  const float* cb    = (const float*)d_in[6];
  float* out = (float*)d_out;

  // Gate tensor lives in the frame-127 region of the output (exactly 1 frame).
  float* gate = out + (size_t)127 * kCAll * kPlane;

  // 8 n * 16 t * 2 g * 2 stripes = 512 blocks, 512 threads (8 waves)
  gate_conv_kernel<<<512, 512, 0, stream>>>(x, gamma, beta, mean, var, cw, cb, gate);
  copy_gate_slice_kernel<<<10, 256, 0, stream>>>((float4*)out);

  const size_t total4 = (size_t)127 * kCAll * kPlane4;  // 25,489,408
  shift_main_kernel<<<(unsigned)((total4 + 255) / 256), 256, 0, stream>>>(
      (const float4*)x, (const float4*)gate, (float4*)out);

  last_frame_kernel<<<(kCAll * kPlane4 + 255) / 256, 256, 0, stream>>>(
      (const float4*)x, (float4*)out);
  fix_hole_kernel<<<10, 256, 0, stream>>>((const float4*)x, (float4*)out);
}